// Round 3
// baseline (113.931 us; speedup 1.0000x reference)
//
#include <hip/hip_runtime.h>

#define BATCH 32768
#define FEAT 512
#define KCENT 2
#define SPW 8                                   // samples per wave (2 rounds of 4)
#define WPB 4                                   // waves per block
#define NBLOCKS (BATCH / (SPW * WPB))           // 1024 blocks = 4 blocks/CU

typedef float vf4 __attribute__((ext_vector_type(4)));

// Non-temporal 16B load for the one-shot x stream (no reuse).
__device__ __forceinline__ vf4 nt_load4(const float* __restrict__ p) {
    return __builtin_nontemporal_load((const vf4*)p);
}

// Single fused kernel: 16-lane-group distance computation (4 samples in
// flight per wave), per-block reduction in LDS, then ONE device-scope
// atomicAdd of the pre-scaled block partial into out[0]. Eliminates the
// second kernel dispatch and the 1024-float workspace round-trip.
__global__ __launch_bounds__(256) void mcl_fused(
    const float* __restrict__ x,
    const int* __restrict__ labels,
    const float* __restrict__ centers,
    float* __restrict__ out)
{
    const int wave = threadIdx.x >> 6;
    const int lane = threadIdx.x & 63;
    const int grp  = lane >> 4;                 // group 0..3 (16 lanes each)
    const int gl   = lane & 15;                 // lane within group
    const int base = (blockIdx.x * WPB + wave) * SPW;

    // coalesced label preload: lanes 0..7 fetch, broadcast via shfl
    int labv = 0;
    if (lane < SPW) labv = labels[base + lane];

    float msum = 0.f;                           // per-lane: sum of own group's mins

#pragma unroll
    for (int r = 0; r < SPW / 4; ++r) {
        const int smp = r * 4 + grp;            // this group's sample this round
        const int lab = __shfl(labv, smp, 64);
        const float* __restrict__ xrow = x + (size_t)(base + smp) * FEAT;
        const float* __restrict__ c0   = centers + (size_t)lab * (KCENT * FEAT);

        float d0 = 0.f, d1 = 0.f;
#pragma unroll
        for (int j = 0; j < 8; ++j) {
            const int off = j * 64 + gl * 4;    // 256B contiguous per group
            const vf4 xv = nt_load4(xrow + off);
            const vf4 a  = *(const vf4*)(c0 + off);
            const vf4 b  = *(const vf4*)(c0 + FEAT + off);
            float e;
            e = xv.x - a.x; d0 += e * e;
            e = xv.y - a.y; d0 += e * e;
            e = xv.z - a.z; d0 += e * e;
            e = xv.w - a.w; d0 += e * e;
            e = xv.x - b.x; d1 += e * e;
            e = xv.y - b.y; d1 += e * e;
            e = xv.z - b.z; d1 += e * e;
            e = xv.w - b.w; d1 += e * e;
        }

        // 4-step xor butterfly within the 16-lane group; afterwards every
        // lane of the group holds the full d0/d1 sums for its sample.
#pragma unroll
        for (int sh = 1; sh <= 8; sh <<= 1) {
            d0 += __shfl_xor(d0, sh, 64);
            d1 += __shfl_xor(d1, sh, 64);
        }
        msum += fminf(d0, d1);
    }

    // combine the 4 groups' accumulated mins (2 DS ops per wave)
    msum += __shfl_xor(msum, 16, 64);
    msum += __shfl_xor(msum, 32, 64);

    __shared__ float sacc[WPB];
    if (lane == 0) sacc[wave] = msum;
    __syncthreads();
    if (threadIdx.x == 0) {
        const float v = (sacc[0] + sacc[1]) + (sacc[2] + sacc[3]);
        atomicAdd(out, v * (1.0f / (float)BATCH));   // device-scope, cross-XCD safe
    }
}

extern "C" void kernel_launch(void* const* d_in, const int* in_sizes, int n_in,
                              void* d_out, int out_size, void* d_ws, size_t ws_size,
                              hipStream_t stream) {
    const float* x       = (const float*)d_in[0];
    const int*   labels  = (const int*)d_in[1];
    const float* centers = (const float*)d_in[2];
    float* out = (float*)d_out;

    // output buffer may be poisoned by the harness; zero the accumulator.
    hipMemsetAsync(out, 0, sizeof(float), stream);
    mcl_fused<<<NBLOCKS, 256, 0, stream>>>(x, labels, centers, out);
}